// Round 9
// baseline (760.228 us; speedup 1.0000x reference)
//
#include <hip/hip_runtime.h>

// Problem constants (fixed by reference)
#define BB 256      // batch
#define TT 1024     // time steps
#define HH 32       // hidden
#define SS 16       // superstep length (steps per barrier)
#define NBK (TT/SS) // 64 blocks of 16 steps
#define NSS (NBK+9) // 73 supersteps (9-stage skew + drain)
#define NT 512      // 8 waves
#define PAD 36      // stream row pad (floats)
#define GPAD 98     // gi row pad (floats)

// Superstep n schedule (stage s handles 16-step block n-s; all edges cross
// exactly one barrier; buffers parity-double-buffered by block index):
//   wv7 : emb gather blk n   -> ebuf ; y2 blk n-2 ; y3 blk n-3
//   wv6 : y1 blk n-1         -> y1s
//   wv3 : gi0 blk n-4        -> gib[0]
//   wv0 : gh0 blk n-5        -> h0s     (serial 16 steps, h in regs)
//   wv4 : gi1 blk n-6        -> gib[1]
//   wv1 : gh1 blk n-7        -> h1s
//   wv5 : gi2 blk n-8        -> gib[2]
//   wv2 : gh2 blk n-9        -> out_seq (direct)
// RULE-#20 AUDIT: no register array is runtime-indexed anywhere. Row loops
// are rolled but touch only memory (global bias loads, LDS result stores).

__device__ __forceinline__ float fast_rcp(float x) { return __builtin_amdgcn_rcpf(x); }
__device__ __forceinline__ float sigm(float x)     { return fast_rcp(1.f + __expf(-x)); }
__device__ __forceinline__ float tanh_fast(float x){ float e = __expf(2.f * x); return 1.f - 2.f * fast_rcp(e + 1.f); }
__device__ __forceinline__ float rlane(float v, int k) {
    return __int_as_float(__builtin_amdgcn_readlane(__float_as_int(v), k));
}

__global__ __launch_bounds__(NT, 1) void rnn_fused(
    const int*   __restrict__ xidx,   // [B,T]
    const float* __restrict__ hid,    // [L,B,H]
    const float* __restrict__ emb,    // [38000,H]
    const float* __restrict__ W1, const float* __restrict__ b1,
    const float* __restrict__ W2, const float* __restrict__ b2,
    const float* __restrict__ W3, const float* __restrict__ b3,
    const float* __restrict__ Wih,    // [L,3H,H]
    const float* __restrict__ Whh,    // [L,3H,H]
    const float* __restrict__ bih,    // [L,3H]
    const float* __restrict__ bhh,    // [L,3H]
    float*       __restrict__ out)    // [B*T*H] ++ [L*B*H]
{
    const int b   = blockIdx.x;
    const int tid = threadIdx.x;
    const int wv  = tid >> 6;
    const int ln  = tid & 63;
    const int lo  = ln & 31;
    const int q   = ln >> 4;           // gi: row-quarter
    const int tg  = ln & 15;           // gi/MLP: time-in-block lane
    const int hh  = ln >> 5;           // MLP: output half

    __shared__ alignas(16) float ebuf[2][SS][PAD];
    __shared__ alignas(16) float y1s [2][SS][PAD];
    __shared__ alignas(16) float y2s [2][SS][PAD];
    __shared__ alignas(16) float y3s [2][SS][PAD];
    __shared__ alignas(16) float h0s [2][SS][PAD];
    __shared__ alignas(16) float h1s [2][SS][PAD];
    __shared__ alignas(16) float gib [3][2][SS][GPAD];

    // ---------------- gh-wave register setup ----------------
    float wA[32], wB[32];
    float biasA = 0.f, biasB = 0.f, v_h = 0.f;
    if (wv < 3) {
        const float4* pA = reinterpret_cast<const float4*>(Whh + (size_t)(wv * 96 + ln) * HH);
        const float4* pB = reinterpret_cast<const float4*>(Whh + (size_t)(wv * 96 + 64 + lo) * HH);
        #pragma unroll
        for (int i = 0; i < 8; ++i) {
            reinterpret_cast<float4*>(wA)[i] = pA[i];
            reinterpret_cast<float4*>(wB)[i] = pB[i];
        }
        biasA = bhh[wv * 96 + ln];
        biasB = bhh[wv * 96 + 64 + lo];
        if (ln < HH) v_h = hid[(size_t)(wv * BB + b) * HH + ln];
    }
    __syncthreads();

    float* const out_seq = out + (size_t)b * TT * HH;
    float* const out_hf  = out + (size_t)BB * TT * HH;

    for (int n = 0; n < NSS; ++n) {
        if (wv < 3) {
            // ============ gh wave, layer wv: 16 serial recurrence steps ========
            const int blk = n - 5 - 2 * wv;
            if (blk >= 0 && blk < NBK) {
                const int p = blk & 1;
                const float* gsrc = &gib[wv][p][0][0];
                __builtin_amdgcn_s_setprio(1);
                for (int t2 = 0; t2 < SS; ++t2) {
                    const float giA = gsrc[t2 * GPAD + ln];        // r/z rows
                    const float giB = gsrc[t2 * GPAD + 64 + lo];   // n rows
                    float a0 = biasA, a1 = 0.f, c0 = biasB, c1 = 0.f;
                    #pragma unroll
                    for (int k = 0; k < 32; k += 2) {
                        const float h0 = rlane(v_h, k), h1 = rlane(v_h, k + 1);
                        a0 = fmaf(wA[k],     h0, a0);
                        a1 = fmaf(wA[k + 1], h1, a1);
                        c0 = fmaf(wB[k],     h0, c0);
                        c1 = fmaf(wB[k + 1], h1, c1);
                    }
                    const float sA  = giA + a0 + a1;     // r-pre / z-pre
                    const float ghB = c0 + c1;           // h_n
                    const float zp  = __shfl_xor(sA, 32);
                    const float r   = sigm(sA);
                    const float z   = sigm(zp);
                    const float nn  = tanh_fast(fmaf(r, ghB, giB));
                    const float hn  = fmaf(z, v_h - nn, nn);
                    v_h = hn;
                    if (ln < HH) {
                        if (wv == 0)      h0s[p][t2][ln] = hn;
                        else if (wv == 1) h1s[p][t2][ln] = hn;
                        else out_seq[(size_t)(blk * SS + t2) * HH + ln] = hn;
                    }
                }
                __builtin_amdgcn_s_setprio(0);
            }
        } else if (wv < 6) {
            // ============ gi wave, layer l: t-in-lanes, rolled row loop ========
            const int l   = wv - 3;
            const int blk = n - 4 - 2 * l;
            if (blk >= 0 && blk < NBK) {
                const int p = blk & 1;
                const float* xsrc = (l == 0) ? &y3s[p][tg][0]
                                  : (l == 1) ? &h0s[p][tg][0]
                                             : &h1s[p][tg][0];
                float xv[32];                      // indexed only by unrolled j
                #pragma unroll
                for (int j = 0; j < 8; ++j)
                    *reinterpret_cast<float4*>(&xv[4 * j]) =
                        *reinterpret_cast<const float4*>(&xsrc[4 * j]);
                const float* wbase = Wih + ((size_t)l * 96 + q * 24) * HH;
                const float* bbase = bih + l * 96 + q * 24;
                float*       gdst  = &gib[l][p][tg][q * 24];
                for (int i = 0; i < 24; ++i) {     // rolled: body touches memory only
                    const float4* wr = reinterpret_cast<const float4*>(wbase + (size_t)i * HH);
                    float a0 = bbase[i], a1 = 0.f, a2 = 0.f, a3 = 0.f;
                    #pragma unroll
                    for (int j = 0; j < 8; ++j) {
                        const float4 w = wr[j];
                        a0 = fmaf(w.x, xv[4 * j + 0], a0);
                        a1 = fmaf(w.y, xv[4 * j + 1], a1);
                        a2 = fmaf(w.z, xv[4 * j + 2], a2);
                        a3 = fmaf(w.w, xv[4 * j + 3], a3);
                    }
                    gdst[i] = (a0 + a1) + (a2 + a3);
                }
            }
        } else if (wv == 6) {
            // ============ y1 wave: blk n-1 ====================================
            const int blk = n - 1;
            if (blk >= 0 && blk < NBK) {
                const int p = blk & 1;
                float ev[32];
                #pragma unroll
                for (int j = 0; j < 8; ++j)
                    *reinterpret_cast<float4*>(&ev[4 * j]) =
                        *reinterpret_cast<const float4*>(&ebuf[p][tg][4 * j]);
                const float* wbse = W1 + (size_t)hh * 16 * HH;
                const float* bbse = b1 + hh * 16;
                float*       dst  = &y1s[p][tg][hh * 16];
                for (int i = 0; i < 16; ++i) {
                    const float4* wr = reinterpret_cast<const float4*>(wbse + (size_t)i * HH);
                    float a0 = bbse[i], a1 = 0.f, a2 = 0.f, a3 = 0.f;
                    #pragma unroll
                    for (int j = 0; j < 8; ++j) {
                        const float4 w = wr[j];
                        a0 = fmaf(w.x, ev[4 * j + 0], a0);
                        a1 = fmaf(w.y, ev[4 * j + 1], a1);
                        a2 = fmaf(w.z, ev[4 * j + 2], a2);
                        a3 = fmaf(w.w, ev[4 * j + 3], a3);
                    }
                    dst[i] = fmaxf((a0 + a1) + (a2 + a3), 0.f);
                }
            }
        } else {
            // ============ wv7: emb gather (n) + y2 (n-2) + y3 (n-3) ===========
            if (n < NBK) {                         // fire gather loads first
                const int pe = n & 1, t0 = n * SS;
                #pragma unroll
                for (int k = 0; k < 2; ++k) {
                    const int task = k * 64 + ln;  // 128 tasks: 16 rows x 8 chunks
                    const int row = task >> 3, qq = task & 7;
                    const int tok = xidx[b * TT + t0 + row];
                    const float4 v = *reinterpret_cast<const float4*>(emb + (size_t)tok * HH + qq * 4);
                    *reinterpret_cast<float4*>(&ebuf[pe][row][qq * 4]) = v;
                }
            }
            const int blk2 = n - 2;                // y2 from y1s
            if (blk2 >= 0 && blk2 < NBK) {
                const int p = blk2 & 1;
                float x1[32];
                #pragma unroll
                for (int j = 0; j < 8; ++j)
                    *reinterpret_cast<float4*>(&x1[4 * j]) =
                        *reinterpret_cast<const float4*>(&y1s[p][tg][4 * j]);
                const float* wbse = W2 + (size_t)hh * 16 * HH;
                const float* bbse = b2 + hh * 16;
                float*       dst  = &y2s[p][tg][hh * 16];
                for (int i = 0; i < 16; ++i) {
                    const float4* wr = reinterpret_cast<const float4*>(wbse + (size_t)i * HH);
                    float a0 = bbse[i], a1 = 0.f, a2 = 0.f, a3 = 0.f;
                    #pragma unroll
                    for (int j = 0; j < 8; ++j) {
                        const float4 w = wr[j];
                        a0 = fmaf(w.x, x1[4 * j + 0], a0);
                        a1 = fmaf(w.y, x1[4 * j + 1], a1);
                        a2 = fmaf(w.z, x1[4 * j + 2], a2);
                        a3 = fmaf(w.w, x1[4 * j + 3], a3);
                    }
                    dst[i] = fmaxf((a0 + a1) + (a2 + a3), 0.f);
                }
            }
            const int blk3 = n - 3;                // y3 from y2s
            if (blk3 >= 0 && blk3 < NBK) {
                const int p = blk3 & 1;
                float x2[32];
                #pragma unroll
                for (int j = 0; j < 8; ++j)
                    *reinterpret_cast<float4*>(&x2[4 * j]) =
                        *reinterpret_cast<const float4*>(&y2s[p][tg][4 * j]);
                const float* wbse = W3 + (size_t)hh * 16 * HH;
                const float* bbse = b3 + hh * 16;
                float*       dst  = &y3s[p][tg][hh * 16];
                for (int i = 0; i < 16; ++i) {
                    const float4* wr = reinterpret_cast<const float4*>(wbse + (size_t)i * HH);
                    float a0 = bbse[i], a1 = 0.f, a2 = 0.f, a3 = 0.f;
                    #pragma unroll
                    for (int j = 0; j < 8; ++j) {
                        const float4 w = wr[j];
                        a0 = fmaf(w.x, x2[4 * j + 0], a0);
                        a1 = fmaf(w.y, x2[4 * j + 1], a1);
                        a2 = fmaf(w.z, x2[4 * j + 2], a2);
                        a3 = fmaf(w.w, x2[4 * j + 3], a3);
                    }
                    dst[i] = fmaxf((a0 + a1) + (a2 + a3), 0.f);
                }
            }
        }
        __syncthreads();   // one barrier per 16 steps
    }

    if (wv < 3 && ln < HH)
        out_hf[(size_t)(wv * BB + b) * HH + ln] = v_h;
}

extern "C" void kernel_launch(void* const* d_in, const int* in_sizes, int n_in,
                              void* d_out, int out_size, void* d_ws, size_t ws_size,
                              hipStream_t stream) {
    const int*   x   = (const int*)  d_in[0];
    const float* hid = (const float*)d_in[1];
    const float* emb = (const float*)d_in[2];
    const float* W1  = (const float*)d_in[3];
    const float* b1  = (const float*)d_in[4];
    const float* W2  = (const float*)d_in[5];
    const float* b2  = (const float*)d_in[6];
    const float* W3  = (const float*)d_in[7];
    const float* b3  = (const float*)d_in[8];
    const float* Wih = (const float*)d_in[9];
    const float* Whh = (const float*)d_in[10];
    const float* bih = (const float*)d_in[11];
    const float* bhh = (const float*)d_in[12];

    rnn_fused<<<dim3(BB), dim3(NT), 0, stream>>>(
        x, hid, emb, W1, b1, W2, b2, W3, b3, Wih, Whh, bih, bhh, (float*)d_out);
}

// Round 10
// 611.123 us; speedup vs baseline: 1.2440x; 1.2440x over previous
//
#include <hip/hip_runtime.h>

// Problem constants (fixed by reference)
#define BB 256      // batch
#define TT 1024     // time steps
#define HH 32       // hidden
#define SS 16       // superstep length (steps per barrier)
#define NBK (TT/SS) // 64 blocks of 16 steps
#define NSS (NBK+8) // 72 supersteps (9-stage skew)
#define NT 512      // 8 waves
#define PAD 36      // stream row pad (floats)
#define GPAD 98     // gi row pad (floats)

// Superstep n schedule (stage s handles 16-step block n-s; every cross-wave
// edge spans exactly one barrier; buffers parity-double-buffered by block):
//   s=0 wv7 : emb gather blk n      -> ebuf
//   s=1 wv6 : y1+y2      blk n-1    -> y2s    (y1 stays in registers)
//   s=2 wv7 : y3         blk n-2    -> y3s
//   s=3 wv3 : gi0        blk n-3    -> gib[0]
//   s=4 wv0 : gh0+gates  blk n-4    -> h0s    (16 serial steps, h in regs)
//   s=5 wv4 : gi1        blk n-5    -> gib[1]
//   s=6 wv1 : gh1+gates  blk n-6    -> h1s
//   s=7 wv5 : gi2        blk n-7    -> gib[2]
//   s=8 wv2 : gh2+gates  blk n-8    -> out_seq (direct store)
// ALL weights register-resident (R9's global reloads were the 25k-cy stall).
// SIMD pairing (wv&3): {gh0,gi1} {gh1,gi2} {gh2,y1y2} {gi0,y3+gather}.

__device__ __forceinline__ float fast_rcp(float x) { return __builtin_amdgcn_rcpf(x); }
__device__ __forceinline__ float sigm(float x)     { return fast_rcp(1.f + __expf(-x)); }
__device__ __forceinline__ float tanh_fast(float x){ float e = __expf(2.f * x); return 1.f - 2.f * fast_rcp(e + 1.f); }
__device__ __forceinline__ float rlane(float v, int k) {
    return __int_as_float(__builtin_amdgcn_readlane(__float_as_int(v), k));
}

__global__ __launch_bounds__(NT, 1) void rnn_fused(
    const int*   __restrict__ xidx,   // [B,T]
    const float* __restrict__ hid,    // [L,B,H]
    const float* __restrict__ emb,    // [38000,H]
    const float* __restrict__ W1, const float* __restrict__ b1,
    const float* __restrict__ W2, const float* __restrict__ b2,
    const float* __restrict__ W3, const float* __restrict__ b3,
    const float* __restrict__ Wih,    // [L,3H,H]
    const float* __restrict__ Whh,    // [L,3H,H]
    const float* __restrict__ bih,    // [L,3H]
    const float* __restrict__ bhh,    // [L,3H]
    float*       __restrict__ out)    // [B*T*H] ++ [L*B*H]
{
    const int b   = blockIdx.x;
    const int tid = threadIdx.x;
    const int wv  = tid >> 6;
    const int ln  = tid & 63;
    const int lo  = ln & 31;

    __shared__ alignas(16) float ebuf[2][SS][PAD];
    __shared__ alignas(16) float y2s [2][SS][PAD];
    __shared__ alignas(16) float y3s [2][SS][PAD];
    __shared__ alignas(16) float h0s [2][SS][PAD];
    __shared__ alignas(16) float h1s [2][SS][PAD];
    __shared__ alignas(16) float gib [3][2][SS][GPAD];

    // ---------------- per-role register-resident weights ----------------
    float wA[32], wB[32];
    float biasA = 0.f, biasB = 0.f, v_h = 0.f;

    if (wv < 3) {                       // gh: Whh rows {ln} and {64+lo}
        const float4* pA = reinterpret_cast<const float4*>(Whh + (size_t)(wv * 96 + ln) * HH);
        const float4* pB = reinterpret_cast<const float4*>(Whh + (size_t)(wv * 96 + 64 + lo) * HH);
        #pragma unroll
        for (int i = 0; i < 8; ++i) {
            reinterpret_cast<float4*>(wA)[i] = pA[i];
            reinterpret_cast<float4*>(wB)[i] = pB[i];
        }
        biasA = bhh[wv * 96 + ln];
        biasB = bhh[wv * 96 + 64 + lo];
        if (ln < HH) v_h = hid[(size_t)(wv * BB + b) * HH + ln];
    } else if (wv < 6) {                // gi: Wih rows {ln} and {64+lo}
        const int l = wv - 3;
        const float4* pA = reinterpret_cast<const float4*>(Wih + (size_t)(l * 96 + ln) * HH);
        const float4* pB = reinterpret_cast<const float4*>(Wih + (size_t)(l * 96 + 64 + lo) * HH);
        #pragma unroll
        for (int i = 0; i < 8; ++i) {
            reinterpret_cast<float4*>(wA)[i] = pA[i];
            reinterpret_cast<float4*>(wB)[i] = pB[i];
        }
        biasA = bih[l * 96 + ln];
        biasB = bih[l * 96 + 64 + lo];
    } else if (wv == 6) {               // y1 (W1 row lo) + y2 (W2 row lo)
        const float4* p1 = reinterpret_cast<const float4*>(W1 + (size_t)lo * HH);
        const float4* p2 = reinterpret_cast<const float4*>(W2 + (size_t)lo * HH);
        #pragma unroll
        for (int i = 0; i < 8; ++i) {
            reinterpret_cast<float4*>(wA)[i] = p1[i];
            reinterpret_cast<float4*>(wB)[i] = p2[i];
        }
        biasA = b1[lo];
        biasB = b2[lo];
    } else {                            // wv7: y3 (W3 row lo) + gather
        const float4* p3 = reinterpret_cast<const float4*>(W3 + (size_t)lo * HH);
        #pragma unroll
        for (int i = 0; i < 8; ++i) reinterpret_cast<float4*>(wA)[i] = p3[i];
        biasA = b3[lo];
    }
    __syncthreads();

    float* const out_seq = out + (size_t)b * TT * HH;
    float* const out_hf  = out + (size_t)BB * TT * HH;

    for (int n = 0; n < NSS; ++n) {
        if (wv < 3) {
            // ============ gh wave, layer wv: 16 serial recurrence steps ========
            const int blk = n - 4 - 2 * wv;
            if (blk >= 0 && blk < NBK) {
                const int p = blk & 1;
                const float* gsrc = &gib[wv][p][0][0];
                __builtin_amdgcn_s_setprio(1);
                for (int t2 = 0; t2 < SS; ++t2) {
                    const float giA = gsrc[t2 * GPAD + ln];        // r/z rows
                    const float giB = gsrc[t2 * GPAD + 64 + lo];   // n rows
                    float a0 = biasA, a1 = 0.f, c0 = biasB, c1 = 0.f;
                    #pragma unroll
                    for (int k = 0; k < 32; k += 2) {
                        const float h0 = rlane(v_h, k), h1 = rlane(v_h, k + 1);
                        a0 = fmaf(wA[k],     h0, a0);
                        a1 = fmaf(wA[k + 1], h1, a1);
                        c0 = fmaf(wB[k],     h0, c0);
                        c1 = fmaf(wB[k + 1], h1, c1);
                    }
                    const float sA  = giA + a0 + a1;     // r-pre / z-pre
                    const float ghB = c0 + c1;           // h_n
                    const float zp  = __shfl_xor(sA, 32);
                    const float r   = sigm(sA);
                    const float z   = sigm(zp);
                    const float nn  = tanh_fast(fmaf(r, ghB, giB));
                    const float hn  = fmaf(z, v_h - nn, nn);
                    v_h = hn;
                    if (ln < HH) {
                        if (wv == 0)      h0s[p][t2][ln] = hn;
                        else if (wv == 1) h1s[p][t2][ln] = hn;
                        else out_seq[(size_t)(blk * SS + t2) * HH + ln] = hn;
                    }
                }
                __builtin_amdgcn_s_setprio(0);
            }
        } else if (wv < 6) {
            // ============ gi wave, layer l: 16 steps, readlane broadcast =======
            const int l   = wv - 3;
            const int blk = n - 3 - 2 * l;
            if (blk >= 0 && blk < NBK) {
                const int p = blk & 1;
                const float* xs = (l == 0) ? &y3s[p][0][0]
                                : (l == 1) ? &h0s[p][0][0]
                                           : &h1s[p][0][0];
                float* gdst = &gib[l][p][0][0];
                for (int t2 = 0; t2 < SS; ++t2) {
                    const float vx = xs[t2 * PAD + lo];  // 32-addr broadcast read
                    float a0 = biasA, a1 = 0.f, c0 = biasB, c1 = 0.f;
                    #pragma unroll
                    for (int k = 0; k < 32; k += 2) {
                        const float x0 = rlane(vx, k), x1 = rlane(vx, k + 1);
                        a0 = fmaf(wA[k],     x0, a0);
                        a1 = fmaf(wA[k + 1], x1, a1);
                        c0 = fmaf(wB[k],     x0, c0);
                        c1 = fmaf(wB[k + 1], x1, c1);
                    }
                    gdst[t2 * GPAD + ln] = a0 + a1;
                    if (ln < 32) gdst[t2 * GPAD + 64 + ln] = c0 + c1;
                }
            }
        } else if (wv == 6) {
            // ============ y1+y2 wave: blk n-1 (y1 never leaves registers) ======
            const int blk = n - 1;
            if (blk >= 0 && blk < NBK) {
                const int p = blk & 1;
                for (int t2 = 0; t2 < SS; ++t2) {
                    const float ve = ebuf[p][t2][lo];
                    float a0 = biasA, a1 = 0.f;
                    #pragma unroll
                    for (int k = 0; k < 32; k += 2) {
                        a0 = fmaf(wA[k],     rlane(ve, k),     a0);
                        a1 = fmaf(wA[k + 1], rlane(ve, k + 1), a1);
                    }
                    const float y1 = fmaxf(a0 + a1, 0.f);   // lane k holds y1[k&31]
                    float c0 = biasB, c1 = 0.f;
                    #pragma unroll
                    for (int k = 0; k < 32; k += 2) {
                        c0 = fmaf(wB[k],     rlane(y1, k),     c0);
                        c1 = fmaf(wB[k + 1], rlane(y1, k + 1), c1);
                    }
                    const float y2 = fmaxf(c0 + c1, 0.f);
                    if (ln < HH) y2s[p][t2][ln] = y2;
                }
            }
        } else {
            // ============ wv7: emb gather blk n, then y3 blk n-2 ===============
            if (n < NBK) {                          // fire gather loads first
                const int pe = n & 1, t0 = n * SS;
                #pragma unroll
                for (int k = 0; k < 2; ++k) {
                    const int task = k * 64 + ln;   // 128 tasks: 16 rows x 8 chunks
                    const int row = task >> 3, qq = task & 7;
                    const int tok = xidx[b * TT + t0 + row];
                    const float4 v = *reinterpret_cast<const float4*>(emb + (size_t)tok * HH + qq * 4);
                    *reinterpret_cast<float4*>(&ebuf[pe][row][qq * 4]) = v;
                }
            }
            const int blk3 = n - 2;
            if (blk3 >= 0 && blk3 < NBK) {
                const int p = blk3 & 1;
                for (int t2 = 0; t2 < SS; ++t2) {
                    const float vx = y2s[p][t2][lo];
                    float a0 = biasA, a1 = 0.f;
                    #pragma unroll
                    for (int k = 0; k < 32; k += 2) {
                        a0 = fmaf(wA[k],     rlane(vx, k),     a0);
                        a1 = fmaf(wA[k + 1], rlane(vx, k + 1), a1);
                    }
                    const float y3 = fmaxf(a0 + a1, 0.f);
                    if (ln < HH) y3s[p][t2][ln] = y3;
                }
            }
        }
        __syncthreads();   // one barrier per 16 steps
    }

    if (wv < 3 && ln < HH)
        out_hf[(size_t)(wv * BB + b) * HH + ln] = v_h;
}

extern "C" void kernel_launch(void* const* d_in, const int* in_sizes, int n_in,
                              void* d_out, int out_size, void* d_ws, size_t ws_size,
                              hipStream_t stream) {
    const int*   x   = (const int*)  d_in[0];
    const float* hid = (const float*)d_in[1];
    const float* emb = (const float*)d_in[2];
    const float* W1  = (const float*)d_in[3];
    const float* b1  = (const float*)d_in[4];
    const float* W2  = (const float*)d_in[5];
    const float* b2  = (const float*)d_in[6];
    const float* W3  = (const float*)d_in[7];
    const float* b3  = (const float*)d_in[8];
    const float* Wih = (const float*)d_in[9];
    const float* Whh = (const float*)d_in[10];
    const float* bih = (const float*)d_in[11];
    const float* bhh = (const float*)d_in[12];

    rnn_fused<<<dim3(BB), dim3(NT), 0, stream>>>(
        x, hid, emb, W1, b1, W2, b2, W3, b3, Wih, Whh, bih, bhh, (float*)d_out);
}

// Round 11
// 488.082 us; speedup vs baseline: 1.5576x; 1.2521x over previous
//
#include <hip/hip_runtime.h>

// Problem constants (fixed by reference)
#define BB 256      // batch
#define TT 1024     // time steps
#define HH 32       // hidden
#define SS 16       // superstep length (steps per barrier)
#define NBK (TT/SS) // 64 blocks of 16 steps
#define NSS (NBK+9) // 73 supersteps (10-stage skew)
#define NT 1024     // 16 waves -> 4 waves per SIMD (latency hiding)
#define SP 32       // stream row stride (floats), 128B rows
#define GP 96       // gi row stride (floats)

// Superstep n schedule (stage s handles 16-step block n-s; one barrier per
// superstep; all buffers parity-double-buffered by block index):
//   wv12 : emb gather blk n     -> ebuf
//   wv9  : y1  blk n-1          -> y1s
//   wv10 : y2  blk n-2          -> y2s
//   wv11 : y3  blk n-3          -> y3s
//   wv3/6: gi0 A/B blk n-4      -> gib[0]
//   wv0  : gh0+gates blk n-5    -> h0s    (16 serial steps, h in regs)
//   wv4/7: gi1 A/B blk n-6      -> gib[1]
//   wv1  : gh1+gates blk n-7    -> h1s
//   wv5/8: gi2 A/B blk n-8      -> gib[2]
//   wv2  : gh2+gates blk n-9    -> out_seq (direct store)
//   wv13-15: idle (barrier only)
// R11 change vs R10: 16 waves (4/SIMD) to hide rlane/LDS/transcendental
// latency; gi split A/B; y1/y2/y3 separate waves; setprio removed (m190).

__device__ __forceinline__ float fast_rcp(float x) { return __builtin_amdgcn_rcpf(x); }
__device__ __forceinline__ float sigm(float x)     { return fast_rcp(1.f + __expf(-x)); }
__device__ __forceinline__ float tanh_fast(float x){ float e = __expf(2.f * x); return 1.f - 2.f * fast_rcp(e + 1.f); }
__device__ __forceinline__ float rlane(float v, int k) {
    return __int_as_float(__builtin_amdgcn_readlane(__float_as_int(v), k));
}

__global__ __launch_bounds__(NT, 4) void rnn_fused(
    const int*   __restrict__ xidx,   // [B,T]
    const float* __restrict__ hid,    // [L,B,H]
    const float* __restrict__ emb,    // [38000,H]
    const float* __restrict__ W1, const float* __restrict__ b1,
    const float* __restrict__ W2, const float* __restrict__ b2,
    const float* __restrict__ W3, const float* __restrict__ b3,
    const float* __restrict__ Wih,    // [L,3H,H]
    const float* __restrict__ Whh,    // [L,3H,H]
    const float* __restrict__ bih,    // [L,3H]
    const float* __restrict__ bhh,    // [L,3H]
    float*       __restrict__ out)    // [B*T*H] ++ [L*B*H]
{
    const int b   = blockIdx.x;
    const int tid = threadIdx.x;
    const int wv  = tid >> 6;
    const int ln  = tid & 63;
    const int lo  = ln & 31;

    __shared__ alignas(16) float ebuf[2][SS][SP];
    __shared__ alignas(16) float y1s [2][SS][SP];
    __shared__ alignas(16) float y2s [2][SS][SP];
    __shared__ alignas(16) float y3s [2][SS][SP];
    __shared__ alignas(16) float h0s [2][SS][SP];
    __shared__ alignas(16) float h1s [2][SS][SP];
    __shared__ alignas(16) float gib [3][2][SS][GP];

    // ---------------- per-role register-resident weights ----------------
    float wA[32], wB[32];
    float biasA = 0.f, biasB = 0.f, v_h = 0.f;

    if (wv < 3) {                       // gh: Whh rows {ln} and {64+lo}
        const float4* pA = reinterpret_cast<const float4*>(Whh + (size_t)(wv * 96 + ln) * HH);
        const float4* pB = reinterpret_cast<const float4*>(Whh + (size_t)(wv * 96 + 64 + lo) * HH);
        #pragma unroll
        for (int i = 0; i < 8; ++i) {
            reinterpret_cast<float4*>(wA)[i] = pA[i];
            reinterpret_cast<float4*>(wB)[i] = pB[i];
        }
        biasA = bhh[wv * 96 + ln];
        biasB = bhh[wv * 96 + 64 + lo];
        if (ln < HH) v_h = hid[(size_t)(wv * BB + b) * HH + ln];
    } else if (wv < 6) {                // giA: Wih row ln (rows 0-63)
        const int l = wv - 3;
        const float4* pA = reinterpret_cast<const float4*>(Wih + (size_t)(l * 96 + ln) * HH);
        #pragma unroll
        for (int i = 0; i < 8; ++i) reinterpret_cast<float4*>(wA)[i] = pA[i];
        biasA = bih[l * 96 + ln];
    } else if (wv < 9) {                // giB: Wih row 64+lo (rows 64-95)
        const int l = wv - 6;
        const float4* pA = reinterpret_cast<const float4*>(Wih + (size_t)(l * 96 + 64 + lo) * HH);
        #pragma unroll
        for (int i = 0; i < 8; ++i) reinterpret_cast<float4*>(wA)[i] = pA[i];
        biasA = bih[l * 96 + 64 + lo];
    } else if (wv < 12) {               // y1/y2/y3: W row lo
        const float* Ws = (wv == 9) ? W1 : (wv == 10) ? W2 : W3;
        const float* bs = (wv == 9) ? b1 : (wv == 10) ? b2 : b3;
        const float4* pA = reinterpret_cast<const float4*>(Ws + (size_t)lo * HH);
        #pragma unroll
        for (int i = 0; i < 8; ++i) reinterpret_cast<float4*>(wA)[i] = pA[i];
        biasA = bs[lo];
    }
    __syncthreads();

    float* const out_seq = out + (size_t)b * TT * HH;
    float* const out_hf  = out + (size_t)BB * TT * HH;

    for (int n = 0; n < NSS; ++n) {
        if (wv < 3) {
            // ============ gh wave, layer wv: 16 serial recurrence steps ========
            const int blk = n - 5 - 2 * wv;
            if (blk >= 0 && blk < NBK) {
                const int p = blk & 1;
                const float* gsrc = &gib[wv][p][0][0];
                for (int t2 = 0; t2 < SS; ++t2) {
                    const float giA = gsrc[t2 * GP + ln];        // r/z rows
                    const float giB = gsrc[t2 * GP + 64 + lo];   // n rows
                    float a0 = biasA, a1 = 0.f, c0 = biasB, c1 = 0.f;
                    #pragma unroll
                    for (int k = 0; k < 32; k += 2) {
                        const float h0 = rlane(v_h, k), h1 = rlane(v_h, k + 1);
                        a0 = fmaf(wA[k],     h0, a0);
                        a1 = fmaf(wA[k + 1], h1, a1);
                        c0 = fmaf(wB[k],     h0, c0);
                        c1 = fmaf(wB[k + 1], h1, c1);
                    }
                    const float sA  = giA + a0 + a1;     // r-pre / z-pre
                    const float ghB = c0 + c1;           // h_n
                    const float zp  = __shfl_xor(sA, 32);
                    const float r   = sigm(sA);
                    const float z   = sigm(zp);
                    const float nn  = tanh_fast(fmaf(r, ghB, giB));
                    const float hn  = fmaf(z, v_h - nn, nn);
                    v_h = hn;
                    if (ln < HH) {
                        if (wv == 0)      h0s[p][t2][ln] = hn;
                        else if (wv == 1) h1s[p][t2][ln] = hn;
                        else out_seq[(size_t)(blk * SS + t2) * HH + ln] = hn;
                    }
                }
            }
        } else if (wv < 6) {
            // ============ giA wave, layer l: rows 0-63 =========================
            const int l   = wv - 3;
            const int blk = n - 4 - 2 * l;
            if (blk >= 0 && blk < NBK) {
                const int p = blk & 1;
                const float* xs = (l == 0) ? &y3s[p][0][0]
                                : (l == 1) ? &h0s[p][0][0]
                                           : &h1s[p][0][0];
                float* gdst = &gib[l][p][0][0];
                for (int t2 = 0; t2 < SS; ++t2) {
                    const float vx = xs[t2 * SP + lo];
                    float a0 = biasA, a1 = 0.f;
                    #pragma unroll
                    for (int k = 0; k < 32; k += 2) {
                        a0 = fmaf(wA[k],     rlane(vx, k),     a0);
                        a1 = fmaf(wA[k + 1], rlane(vx, k + 1), a1);
                    }
                    gdst[t2 * GP + ln] = a0 + a1;
                }
            }
        } else if (wv < 9) {
            // ============ giB wave, layer l: rows 64-95 (n-gates) ==============
            const int l   = wv - 6;
            const int blk = n - 4 - 2 * l;
            if (blk >= 0 && blk < NBK) {
                const int p = blk & 1;
                const float* xs = (l == 0) ? &y3s[p][0][0]
                                : (l == 1) ? &h0s[p][0][0]
                                           : &h1s[p][0][0];
                float* gdst = &gib[l][p][0][0];
                for (int t2 = 0; t2 < SS; ++t2) {
                    const float vx = xs[t2 * SP + lo];
                    float a0 = biasA, a1 = 0.f;
                    #pragma unroll
                    for (int k = 0; k < 32; k += 2) {
                        a0 = fmaf(wA[k],     rlane(vx, k),     a0);
                        a1 = fmaf(wA[k + 1], rlane(vx, k + 1), a1);
                    }
                    if (ln < 32) gdst[t2 * GP + 64 + ln] = a0 + a1;
                }
            }
        } else if (wv < 12) {
            // ============ y1/y2/y3 waves =======================================
            const int s   = wv - 9;            // 0,1,2
            const int blk = n - 1 - s;
            if (blk >= 0 && blk < NBK) {
                const int p = blk & 1;
                const float* xs = (s == 0) ? &ebuf[p][0][0]
                                : (s == 1) ? &y1s[p][0][0]
                                           : &y2s[p][0][0];
                float* dst = (s == 0) ? &y1s[p][0][0]
                           : (s == 1) ? &y2s[p][0][0]
                                      : &y3s[p][0][0];
                for (int t2 = 0; t2 < SS; ++t2) {
                    const float vx = xs[t2 * SP + lo];
                    float a0 = biasA, a1 = 0.f;
                    #pragma unroll
                    for (int k = 0; k < 32; k += 2) {
                        a0 = fmaf(wA[k],     rlane(vx, k),     a0);
                        a1 = fmaf(wA[k + 1], rlane(vx, k + 1), a1);
                    }
                    const float y = fmaxf(a0 + a1, 0.f);
                    if (ln < 32) dst[t2 * SP + ln] = y;
                }
            }
        } else if (wv == 12) {
            // ============ emb gather blk n =====================================
            if (n < NBK) {
                const int pe = n & 1, t0 = n * SS;
                #pragma unroll
                for (int k = 0; k < 2; ++k) {
                    const int task = k * 64 + ln;   // 128 tasks: 16 rows x 8 chunks
                    const int row = task >> 3, qq = task & 7;
                    const int tok = xidx[b * TT + t0 + row];
                    const float4 v = *reinterpret_cast<const float4*>(emb + (size_t)tok * HH + qq * 4);
                    *reinterpret_cast<float4*>(&ebuf[pe][row][qq * 4]) = v;
                }
            }
        }
        // wv 13-15: idle
        __syncthreads();   // one barrier per 16 steps
    }

    if (wv < 3 && ln < HH)
        out_hf[(size_t)(wv * BB + b) * HH + ln] = v_h;
}

extern "C" void kernel_launch(void* const* d_in, const int* in_sizes, int n_in,
                              void* d_out, int out_size, void* d_ws, size_t ws_size,
                              hipStream_t stream) {
    const int*   x   = (const int*)  d_in[0];
    const float* hid = (const float*)d_in[1];
    const float* emb = (const float*)d_in[2];
    const float* W1  = (const float*)d_in[3];
    const float* b1  = (const float*)d_in[4];
    const float* W2  = (const float*)d_in[5];
    const float* b2  = (const float*)d_in[6];
    const float* W3  = (const float*)d_in[7];
    const float* b3  = (const float*)d_in[8];
    const float* Wih = (const float*)d_in[9];
    const float* Whh = (const float*)d_in[10];
    const float* bih = (const float*)d_in[11];
    const float* bhh = (const float*)d_in[12];

    rnn_fused<<<dim3(BB), dim3(NT), 0, stream>>>(
        x, hid, emb, W1, b1, W2, b2, W3, b3, Wih, Whh, bih, bhh, (float*)d_out);
}